// Round 4
// baseline (249.128 us; speedup 1.0000x reference)
//
#include <hip/hip_runtime.h>

// CASREL loss. B=32,S=512,H=1024,R=64 -> scalar fp32 loss.
// R4: register-lean streaming MFMA GEMM. 1024 blocks x 320 threads; each
// wave owns 16 rows x 32 cols x K=1024 (2 accumulators only -> no spills).
// No LDS staging, no barriers in the GEMM. B pre-swizzled [k/32][160][32]
// bf16 so fragment loads are contiguous 1KB with immediate offsets.
// 2 dispatches total (ticket-based finalize).

#define B_  32
#define S_  512
#define H_  1024
#define R_  64
#define M_  (B_ * S_)      // 16384 rows
#define NPAD 160           // 130 valid cols padded to 10*16
#define NVALID 130
#define NBLK (M_ / 16)     // 1024 main blocks

typedef __attribute__((ext_vector_type(4))) float  floatx4;
typedef __attribute__((ext_vector_type(8))) short  short8;     // 8 bf16

__device__ __forceinline__ unsigned short f2bf(float f) {
    unsigned int u = __float_as_uint(f);
    u = (u + 0x7FFFu + ((u >> 16) & 1u)) >> 16;   // RNE
    return (unsigned short)u;
}

// ---- K1 (fused): blocks 0..159: transpose/pad weights into swizzled
//      Wt3[k/32][160][32] bf16; blocks 160..191: per-batch rowBias;
//      block 0 also zeroes accum + ticket ----
__global__ __launch_bounds__(256) void prep_kernel(
        const float* __restrict__ ctx,  const float* __restrict__ head,
        const float* __restrict__ tail,
        const float* __restrict__ Ws_h, const float* __restrict__ Ws_t,
        const float* __restrict__ Wo_h, const float* __restrict__ Wo_t,
        const float* __restrict__ bo_h, const float* __restrict__ bo_t,
        const float* __restrict__ bs_h, const float* __restrict__ bs_t,
        unsigned short* __restrict__ Wt3, float* __restrict__ rowBias,
        float* __restrict__ accum, int* __restrict__ ticket) {
    const int blk = blockIdx.x, tid = threadIdx.x;
    if (blk == 0) {
        if (tid < 2) accum[tid] = 0.0f;
        if (tid == 2) *ticket = 0;
    }
    if (blk < NPAD) {
        const int n = blk;
        for (int k = tid; k < H_; k += 256) {
            float v;
            if (n < 64)        v = Wo_h[k * R_ + n];
            else if (n < 128)  v = Wo_t[k * R_ + (n - 64)];
            else if (n == 128) v = Ws_h[k];
            else if (n == 129) v = Ws_t[k];
            else               v = 0.0f;
            Wt3[(k >> 5) * (NPAD * 32) + n * 32 + (k & 31)] = f2bf(v);
        }
        return;
    }
    // ---- subject path, b = blk - 160 ----
    const int b = blk - NPAD;
    __shared__ float subj[H_];
    __shared__ float part[256];
    __shared__ int cnt;
    __shared__ int   sidx[4];
    __shared__ float sw[4];
    if (tid == 0) cnt = 0;
    __syncthreads();
    for (int s = tid; s < S_; s += 256) {
        float w = 0.5f * (head[b * S_ + s] + tail[b * S_ + s]);
        if (w != 0.0f) {
            int i = atomicAdd(&cnt, 1);
            if (i < 4) { sidx[i] = s; sw[i] = w; }
        }
    }
    __syncthreads();
    const int nnz = cnt < 4 ? cnt : 4;
    for (int h = tid; h < H_; h += 256) {
        float a = 0.0f;
        for (int i = 0; i < nnz; i++)
            a += sw[i] * ctx[((size_t)b * S_ + sidx[i]) * H_ + h];
        subj[h] = a;
    }
    __syncthreads();
    // GEMV subj[1024] @ W[1024][128]: tid = hf*128 + c, coalesced W reads
    {
        const int c = tid & 127, hf = tid >> 7;
        const float* W = (c < 64) ? (Wo_h + c) : (Wo_t + (c - 64));
        float a = 0.0f;
        const int k0 = hf * 512;
#pragma unroll 16
        for (int k = k0; k < k0 + 512; k++)
            a += subj[k] * W[(size_t)k * R_];
        part[tid] = a;
    }
    __syncthreads();
    if (tid < NPAD) {
        float v;
        if (tid < 128)
            v = part[tid] + part[128 + tid] + (tid < 64 ? bo_h[tid] : bo_t[tid - 64]);
        else if (tid == 128) v = bs_h[0];
        else if (tid == 129) v = bs_t[0];
        else                 v = 0.0f;
        rowBias[b * NPAD + tid] = v;
    }
}

// ---- K2: barrier-free GEMM + BCE + reduction + ticket-finalize ----
__global__ __launch_bounds__(320, 5) void main_kernel(
        const float* __restrict__ ctx, const unsigned short* __restrict__ Wt3,
        const float* __restrict__ rowBias, const float* __restrict__ masks,
        const float* __restrict__ ash, const float* __restrict__ ast,
        const float* __restrict__ oh, const float* __restrict__ ot,
        float* __restrict__ accum, int* __restrict__ ticket,
        float* __restrict__ out) {
    const int tid  = threadIdx.x;
    const int wave = tid >> 6, lane = tid & 63;
    const int lr = lane & 15, q = lane >> 4;
    const int gm0 = blockIdx.x << 4;       // 16 rows per block
    const int b   = gm0 >> 9;

    const float* aP = ctx + (size_t)(gm0 + lr) * H_ + q * 8;
    const unsigned short* bP = Wt3 + (wave * 32 + lr) * 32 + q * 8;

    floatx4 acc0 = (floatx4){0.f, 0.f, 0.f, 0.f};
    floatx4 acc1 = (floatx4){0.f, 0.f, 0.f, 0.f};

#pragma unroll 4
    for (int it = 0; it < 32; ++it) {
        const float4 a0 = *(const float4*)(aP);
        const float4 a1 = *(const float4*)(aP + 4);
        const short8 b0 = *(const short8*)(bP);
        const short8 b1 = *(const short8*)(bP + 512);   // +1KB (next 16 cols)
        aP += 32;
        bP += NPAD * 32;
        short8 af;
        af[0] = (short)f2bf(a0.x); af[1] = (short)f2bf(a0.y);
        af[2] = (short)f2bf(a0.z); af[3] = (short)f2bf(a0.w);
        af[4] = (short)f2bf(a1.x); af[5] = (short)f2bf(a1.y);
        af[6] = (short)f2bf(a1.z); af[7] = (short)f2bf(a1.w);
        acc0 = __builtin_amdgcn_mfma_f32_16x16x32_bf16(af, b0, acc0, 0, 0, 0);
        acc1 = __builtin_amdgcn_mfma_f32_16x16x32_bf16(af, b1, acc1, 0, 0, 0);
    }

    // epilogue: per-wave BCE over its 16x32 tile, shuffle-reduce, 1 atomic
    float lsum = 0.0f;
#pragma unroll
    for (int tt = 0; tt < 2; tt++) {
        const int col = wave * 32 + tt * 16 + lr;
        const floatx4 a = tt ? acc1 : acc0;
        if (col < NVALID) {
            const float rb = rowBias[b * NPAD + col];
#pragma unroll
            for (int i = 0; i < 4; i++) {
                const int row = gm0 + q * 4 + i;
                const float l = a[i] + rb;
                float tgt;
                if (col < 64)        tgt = oh[row * R_ + col];
                else if (col < 128)  tgt = ot[row * R_ + (col - 64)];
                else if (col == 128) tgt = ash[row];
                else                 tgt = ast[row];
                const float bce = fmaxf(l, 0.0f) - l * tgt
                                + log1pf(__expf(-fabsf(l)));
                lsum += bce * masks[row];
            }
        }
    }
#pragma unroll
    for (int o = 32; o > 0; o >>= 1) lsum += __shfl_down(lsum, o, 64);
    if (lane == 0) atomicAdd(&accum[0], lsum);

    // mask partial sum (one wave per block)
    if (wave == 0 && lane < 16) {
        float mv = masks[gm0 + lane];
#pragma unroll
        for (int o = 8; o > 0; o >>= 1) mv += __shfl_down(mv, o, 64);
        if (lane == 0) atomicAdd(&accum[1], mv);
    }

    __syncthreads();   // all waves' atomics drained (vmcnt flushed pre-barrier)
    if (tid == 0) {
        __threadfence();
        const int old = atomicAdd(ticket, 1);
        if (old == NBLK - 1) {
            const float s = atomicAdd(&accum[0], 0.0f);   // coherent read
            const float m = atomicAdd(&accum[1], 0.0f);
            out[0] = s / m;
        }
    }
}

extern "C" void kernel_launch(void* const* d_in, const int* in_sizes, int n_in,
                              void* d_out, int out_size, void* d_ws, size_t ws_size,
                              hipStream_t stream) {
    const float* ctx   = (const float*)d_in[0];
    const float* masks = (const float*)d_in[1];
    const float* ash   = (const float*)d_in[2];
    const float* ast   = (const float*)d_in[3];
    const float* sh    = (const float*)d_in[4];
    const float* st    = (const float*)d_in[5];
    const float* oh    = (const float*)d_in[6];
    const float* ot    = (const float*)d_in[7];
    const float* Ws_h  = (const float*)d_in[8];
    const float* bs_h  = (const float*)d_in[9];
    const float* Ws_t  = (const float*)d_in[10];
    const float* bs_t  = (const float*)d_in[11];
    const float* Wo_h  = (const float*)d_in[12];
    const float* bo_h  = (const float*)d_in[13];
    const float* Wo_t  = (const float*)d_in[14];
    const float* bo_t  = (const float*)d_in[15];
    float* out = (float*)d_out;

    char* ws = (char*)d_ws;
    float* accum   = (float*)(ws + 0);          // [0]=loss sum, [1]=mask sum
    int*   ticket  = (int*)(ws + 64);
    float* rowBias = (float*)(ws + 256);        // [32][160] fp32
    unsigned short* Wt3 = (unsigned short*)(ws + 256 + 32 * NPAD * 4); // [32][160][32] bf16

    prep_kernel<<<NPAD + B_, 256, 0, stream>>>(ctx, sh, st, Ws_h, Ws_t,
                                               Wo_h, Wo_t, bo_h, bo_t, bs_h, bs_t,
                                               Wt3, rowBias, accum, ticket);
    main_kernel<<<NBLK, 320, 0, stream>>>(ctx, Wt3, rowBias, masks,
                                          ash, ast, oh, ot, accum, ticket, out);
}

// Round 5
// 200.997 us; speedup vs baseline: 1.2395x; 1.2395x over previous
//
#include <hip/hip_runtime.h>

// CASREL loss. B=32,S=512,H=1024,R=64 -> scalar fp32 loss.
// R5: m97-style async-DMA staged MFMA GEMM. 1024 blocks (4 co-resident/CU)
// = 512 row-tiles (32 rows) x 2 col-halves (96 of NPAD=192 cols).
// B staged via global_load_lds (16B DMA, no VGPR round-trip); A staged via
// coalesced float4 loads + v_perm bf16 pack + ds_write (padded stride 72).
// K-loop: 16 iters of BK=64, 2 barriers each; 4 blocks/CU overlap the drains.

#define B_  32
#define S_  512
#define H_  1024
#define R_  64
#define M_  (B_ * S_)      // 16384 rows
#define NPAD 192           // 130 valid cols padded to 12*16
#define NVALID 130
#define NBLK 1024          // 512 row-tiles x 2 col-halves

typedef __attribute__((ext_vector_type(4))) float  floatx4;
typedef __attribute__((ext_vector_type(8))) short  short8;     // 8 bf16

__device__ __forceinline__ unsigned short f2bf(float f) {
    unsigned int u = __float_as_uint(f);
    u = (u + 0x7FFFu + ((u >> 16) & 1u)) >> 16;   // RNE
    return (unsigned short)u;
}

__device__ __forceinline__ void gload16(const void* g, void* l) {
    __builtin_amdgcn_global_load_lds(
        (const __attribute__((address_space(1))) unsigned int*)g,
        (__attribute__((address_space(3))) unsigned int*)l, 16, 0, 0);
}

// ---- K1 (fused): blocks 0..191: transpose/pad weights into swizzled
//      Wt3[k/32][192][32] bf16 (cols >=130 zero); blocks 192..223: rowBias;
//      block 0 zeroes accum + ticket ----
__global__ __launch_bounds__(256) void prep_kernel(
        const float* __restrict__ ctx,  const float* __restrict__ head,
        const float* __restrict__ tail,
        const float* __restrict__ Ws_h, const float* __restrict__ Ws_t,
        const float* __restrict__ Wo_h, const float* __restrict__ Wo_t,
        const float* __restrict__ bo_h, const float* __restrict__ bo_t,
        const float* __restrict__ bs_h, const float* __restrict__ bs_t,
        unsigned short* __restrict__ Wt3, float* __restrict__ rowBias,
        float* __restrict__ accum, int* __restrict__ ticket) {
    const int blk = blockIdx.x, tid = threadIdx.x;
    if (blk == 0) {
        if (tid < 2) accum[tid] = 0.0f;
        if (tid == 2) *ticket = 0;
    }
    if (blk < NPAD) {
        const int n = blk;
        for (int k = tid; k < H_; k += 256) {
            float v;
            if (n < 64)        v = Wo_h[k * R_ + n];
            else if (n < 128)  v = Wo_t[k * R_ + (n - 64)];
            else if (n == 128) v = Ws_h[k];
            else if (n == 129) v = Ws_t[k];
            else               v = 0.0f;
            Wt3[(k >> 5) * (NPAD * 32) + n * 32 + (k & 31)] = f2bf(v);
        }
        return;
    }
    // ---- subject path, b = blk - 192 ----
    const int b = blk - NPAD;
    __shared__ float subj[H_];
    __shared__ float part[256];
    __shared__ int cnt;
    __shared__ int   sidx[4];
    __shared__ float sw[4];
    if (tid == 0) cnt = 0;
    __syncthreads();
    for (int s = tid; s < S_; s += 256) {
        float w = 0.5f * (head[b * S_ + s] + tail[b * S_ + s]);
        if (w != 0.0f) {
            int i = atomicAdd(&cnt, 1);
            if (i < 4) { sidx[i] = s; sw[i] = w; }
        }
    }
    __syncthreads();
    const int nnz = cnt < 4 ? cnt : 4;
    for (int h = tid; h < H_; h += 256) {
        float a = 0.0f;
        for (int i = 0; i < nnz; i++)
            a += sw[i] * ctx[((size_t)b * S_ + sidx[i]) * H_ + h];
        subj[h] = a;
    }
    __syncthreads();
    // GEMV subj[1024] @ W[1024][128]: tid = hf*128 + c, coalesced W reads
    {
        const int c = tid & 127, hf = tid >> 7;
        const float* W = (c < 64) ? (Wo_h + c) : (Wo_t + (c - 64));
        float a = 0.0f;
        const int k0 = hf * 512;
#pragma unroll 16
        for (int k = k0; k < k0 + 512; k++)
            a += subj[k] * W[(size_t)k * R_];
        part[tid] = a;
    }
    __syncthreads();
    if (tid < NPAD) {
        float v;
        if (tid < 128)
            v = part[tid] + part[128 + tid] + (tid < 64 ? bo_h[tid] : bo_t[tid - 64]);
        else if (tid == 128) v = bs_h[0];
        else if (tid == 129) v = bs_t[0];
        else                 v = 0.0f;
        rowBias[b * NPAD + tid] = v;
    }
}

// ---- K2: DMA-staged GEMM + BCE + reduction + ticket-finalize ----
__global__ __launch_bounds__(256) void main_kernel(
        const float* __restrict__ ctx, const unsigned short* __restrict__ Wt3,
        const float* __restrict__ rowBias, const float* __restrict__ masks,
        const float* __restrict__ ash, const float* __restrict__ ast,
        const float* __restrict__ oh, const float* __restrict__ ot,
        float* __restrict__ accum, int* __restrict__ ticket,
        float* __restrict__ out) {
    __shared__ __align__(16) unsigned short Abf[32 * 72];        // 4.5 KB bf16, pad 72
    __shared__ __align__(16) unsigned short Bsm[2 * 96 * 32];    // 12 KB bf16 (DMA dest)

    const int tid  = threadIdx.x;
    const int wave = tid >> 6, lane = tid & 63;
    const int lr = lane & 15, q = lane >> 4;
    const int rh = wave & 1;                  // row half (16 rows)
    const int ch = wave >> 1;                 // col half (48 cols)
    const int cb  = blockIdx.x & 1;           // 96-col block half
    const int gm0 = (blockIdx.x >> 1) << 5;   // 32 rows per block
    const int b   = gm0 >> 9;

    // A staging: thread covers 8 consecutive floats of one row
    const int arow = tid >> 3, ac8 = (tid & 7) * 8;
    const float* aG = ctx + (size_t)(gm0 + arow) * H_ + ac8;
    unsigned short* aL = &Abf[arow * 72 + ac8];

    // B staging: 3 x 16B DMA per thread; LDS slot idx3 = j*256+tid
    const unsigned short* bG[3];
    unsigned short* bL[3];
#pragma unroll
    for (int j = 0; j < 3; j++) {
        const int idx3 = j * 256 + tid;
        const int kcH  = idx3 / 384;               // 0 or 1 (wave-aligned)
        const int rem  = idx3 - kcH * 384;
        const int col96 = rem >> 2, part = rem & 3;
        bG[j] = Wt3 + ((size_t)kcH * NPAD + cb * 96 + col96) * 32 + part * 8;
        bL[j] = &Bsm[(size_t)(j * 256 + wave * 64) * 8];   // wave-uniform base
    }

    // fragment offsets
    const int aro = (rh * 16 + lr) * 72 + q * 8;
    int bro[3];
#pragma unroll
    for (int t = 0; t < 3; t++)
        bro[t] = (ch * 48 + t * 16 + lr) * 32 + q * 8;

    floatx4 acc[3];
#pragma unroll
    for (int t = 0; t < 3; t++) acc[t] = (floatx4){0.f, 0.f, 0.f, 0.f};

    for (int it = 0; it < 16; ++it) {
        __syncthreads();   // prev compute done reading LDS
        // B: async DMA global->LDS (no VGPR round-trip)
#pragma unroll
        for (int j = 0; j < 3; j++) gload16(bG[j], bL[j]);
        // A: coalesced loads + truncate-pack to bf16 + one ds_write_b128
        const float4 a0 = *(const float4*)(aG);
        const float4 a1 = *(const float4*)(aG + 4);
        unsigned int p0 = __builtin_amdgcn_perm(__float_as_uint(a0.y), __float_as_uint(a0.x), 0x07060302u);
        unsigned int p1 = __builtin_amdgcn_perm(__float_as_uint(a0.w), __float_as_uint(a0.z), 0x07060302u);
        unsigned int p2 = __builtin_amdgcn_perm(__float_as_uint(a1.y), __float_as_uint(a1.x), 0x07060302u);
        unsigned int p3 = __builtin_amdgcn_perm(__float_as_uint(a1.w), __float_as_uint(a1.z), 0x07060302u);
        *(uint4*)aL = (uint4){p0, p1, p2, p3};
        aG += 64;
#pragma unroll
        for (int j = 0; j < 3; j++) bG[j] += 2 * NPAD * 32;
        __syncthreads();   // staging (incl. DMA vmcnt drain) visible
#pragma unroll
        for (int kk = 0; kk < 2; kk++) {
            const short8 afr = *(const short8*)&Abf[aro + kk * 32];
#pragma unroll
            for (int t = 0; t < 3; t++) {
                const short8 bfr = *(const short8*)&Bsm[kk * 3072 + bro[t]];
                acc[t] = __builtin_amdgcn_mfma_f32_16x16x32_bf16(afr, bfr, acc[t], 0, 0, 0);
            }
        }
    }

    // epilogue: logits -> BCE * mask -> per-wave reduce -> atomic
    float lsum = 0.0f;
#pragma unroll
    for (int t = 0; t < 3; t++) {
        const int col = cb * 96 + ch * 48 + t * 16 + lr;
        if (col < NVALID) {
            const float rb = rowBias[b * NPAD + col];
#pragma unroll
            for (int i = 0; i < 4; i++) {
                const int row = gm0 + rh * 16 + q * 4 + i;
                const float l = acc[t][i] + rb;
                float tgt;
                if (col < 64)        tgt = oh[row * R_ + col];
                else if (col < 128)  tgt = ot[row * R_ + (col - 64)];
                else if (col == 128) tgt = ash[row];
                else                 tgt = ast[row];
                const float bce = fmaxf(l, 0.0f) - l * tgt
                                + log1pf(__expf(-fabsf(l)));
                lsum += bce * masks[row];
            }
        }
    }
#pragma unroll
    for (int o = 32; o > 0; o >>= 1) lsum += __shfl_down(lsum, o, 64);
    if (lane == 0) atomicAdd(&accum[0], lsum);

    // mask sum: one wave of each cb==0 block covers its 32 rows
    if (cb == 0 && wave == 0) {
        float mv = (lane < 32) ? masks[gm0 + lane] : 0.0f;
#pragma unroll
        for (int o = 32; o > 0; o >>= 1) mv += __shfl_down(mv, o, 64);
        if (lane == 0) atomicAdd(&accum[1], mv);
    }

    __syncthreads();
    if (tid == 0) {
        __threadfence();
        const int old = atomicAdd(ticket, 1);
        if (old == NBLK - 1) {
            const float s = atomicAdd(&accum[0], 0.0f);   // coherent read
            const float m = atomicAdd(&accum[1], 0.0f);
            out[0] = s / m;
        }
    }
}

extern "C" void kernel_launch(void* const* d_in, const int* in_sizes, int n_in,
                              void* d_out, int out_size, void* d_ws, size_t ws_size,
                              hipStream_t stream) {
    const float* ctx   = (const float*)d_in[0];
    const float* masks = (const float*)d_in[1];
    const float* ash   = (const float*)d_in[2];
    const float* ast   = (const float*)d_in[3];
    const float* sh    = (const float*)d_in[4];
    const float* st    = (const float*)d_in[5];
    const float* oh    = (const float*)d_in[6];
    const float* ot    = (const float*)d_in[7];
    const float* Ws_h  = (const float*)d_in[8];
    const float* bs_h  = (const float*)d_in[9];
    const float* Ws_t  = (const float*)d_in[10];
    const float* bs_t  = (const float*)d_in[11];
    const float* Wo_h  = (const float*)d_in[12];
    const float* bo_h  = (const float*)d_in[13];
    const float* Wo_t  = (const float*)d_in[14];
    const float* bo_t  = (const float*)d_in[15];
    float* out = (float*)d_out;

    char* ws = (char*)d_ws;
    float* accum   = (float*)(ws + 0);          // [0]=loss sum, [1]=mask sum
    int*   ticket  = (int*)(ws + 64);
    float* rowBias = (float*)(ws + 256);        // [32][192] fp32
    unsigned short* Wt3 = (unsigned short*)(ws + 256 + 32 * NPAD * 4); // [32][192][32] bf16

    prep_kernel<<<NPAD + B_, 256, 0, stream>>>(ctx, sh, st, Ws_h, Ws_t,
                                               Wo_h, Wo_t, bo_h, bo_t, bs_h, bs_t,
                                               Wt3, rowBias, accum, ticket);
    main_kernel<<<NBLK, 256, 0, stream>>>(ctx, Wt3, rowBias, masks,
                                          ash, ast, oh, ot, accum, ticket, out);
}

// Round 6
// 179.891 us; speedup vs baseline: 1.3849x; 1.1173x over previous
//
#include <hip/hip_runtime.h>

// CASREL loss. B=32,S=512,H=1024,R=64 -> scalar fp32 loss.
// R6: deep-queue streaming MFMA GEMM. Diagnosis of R1-R5: all rounds were
// outstanding-request limited (~1 load in flight/wave -> ~700 GB/s HBM).
// Fix: __launch_bounds__(256,2) (VGPR budget 256) + manual 4-iteration
// load batching (32 loads in flight before first consume). No LDS staging,
// no barriers in the GEMM. 512 blocks x 4 waves; wave = 16 rows x 96 cols.

#define B_  32
#define S_  512
#define H_  1024
#define R_  64
#define M_  (B_ * S_)      // 16384 rows
#define NPAD 192           // 130 valid cols padded to 12*16
#define NVALID 130
#define NBLK 512           // 512 row-tiles of 32 rows

typedef __attribute__((ext_vector_type(4))) float  floatx4;
typedef __attribute__((ext_vector_type(8))) short  short8;     // 8 bf16

__device__ __forceinline__ unsigned short f2bf(float f) {
    unsigned int u = __float_as_uint(f);
    u = (u + 0x7FFFu + ((u >> 16) & 1u)) >> 16;   // RNE
    return (unsigned short)u;
}

// ---- K1 (fused): blocks 0..191: transpose/pad weights into swizzled
//      Wt3[k/32][192][32] bf16 (cols >=130 zero); blocks 192..223: rowBias;
//      block 0 zeroes accum + ticket ----
__global__ __launch_bounds__(256) void prep_kernel(
        const float* __restrict__ ctx,  const float* __restrict__ head,
        const float* __restrict__ tail,
        const float* __restrict__ Ws_h, const float* __restrict__ Ws_t,
        const float* __restrict__ Wo_h, const float* __restrict__ Wo_t,
        const float* __restrict__ bo_h, const float* __restrict__ bo_t,
        const float* __restrict__ bs_h, const float* __restrict__ bs_t,
        unsigned short* __restrict__ Wt3, float* __restrict__ rowBias,
        float* __restrict__ accum, int* __restrict__ ticket) {
    const int blk = blockIdx.x, tid = threadIdx.x;
    if (blk == 0) {
        if (tid < 2) accum[tid] = 0.0f;
        if (tid == 2) *ticket = 0;
    }
    if (blk < NPAD) {
        const int n = blk;
        for (int k = tid; k < H_; k += 256) {
            float v;
            if (n < 64)        v = Wo_h[k * R_ + n];
            else if (n < 128)  v = Wo_t[k * R_ + (n - 64)];
            else if (n == 128) v = Ws_h[k];
            else if (n == 129) v = Ws_t[k];
            else               v = 0.0f;
            Wt3[(k >> 5) * (NPAD * 32) + n * 32 + (k & 31)] = f2bf(v);
        }
        return;
    }
    // ---- subject path, b = blk - 192 ----
    const int b = blk - NPAD;
    __shared__ float subj[H_];
    __shared__ float part[256];
    __shared__ int cnt;
    __shared__ int   sidx[4];
    __shared__ float sw[4];
    if (tid == 0) cnt = 0;
    __syncthreads();
    for (int s = tid; s < S_; s += 256) {
        float w = 0.5f * (head[b * S_ + s] + tail[b * S_ + s]);
        if (w != 0.0f) {
            int i = atomicAdd(&cnt, 1);
            if (i < 4) { sidx[i] = s; sw[i] = w; }
        }
    }
    __syncthreads();
    const int nnz = cnt < 4 ? cnt : 4;
    for (int h = tid; h < H_; h += 256) {
        float a = 0.0f;
        for (int i = 0; i < nnz; i++)
            a += sw[i] * ctx[((size_t)b * S_ + sidx[i]) * H_ + h];
        subj[h] = a;
    }
    __syncthreads();
    // GEMV subj[1024] @ W[1024][128]: tid = hf*128 + c, coalesced W reads
    {
        const int c = tid & 127, hf = tid >> 7;
        const float* W = (c < 64) ? (Wo_h + c) : (Wo_t + (c - 64));
        float a = 0.0f;
        const int k0 = hf * 512;
#pragma unroll 16
        for (int k = k0; k < k0 + 512; k++)
            a += subj[k] * W[(size_t)k * R_];
        part[tid] = a;
    }
    __syncthreads();
    if (tid < NPAD) {
        float v;
        if (tid < 128)
            v = part[tid] + part[128 + tid] + (tid < 64 ? bo_h[tid] : bo_t[tid - 64]);
        else if (tid == 128) v = bs_h[0];
        else if (tid == 129) v = bs_t[0];
        else                 v = 0.0f;
        rowBias[b * NPAD + tid] = v;
    }
}

// ---- K2: deep-queue GEMM + BCE + reduction + ticket-finalize ----
// launch_bounds(256,2): VGPR budget 256 -> room for 4-deep load batches.
__global__ __launch_bounds__(256, 2) void main_kernel(
        const float* __restrict__ ctx, const unsigned short* __restrict__ Wt3,
        const float* __restrict__ rowBias, const float* __restrict__ masks,
        const float* __restrict__ ash, const float* __restrict__ ast,
        const float* __restrict__ oh, const float* __restrict__ ot,
        float* __restrict__ accum, int* __restrict__ ticket,
        float* __restrict__ out) {
    __shared__ float rbuf[4];
    const int tid  = threadIdx.x;
    const int wave = tid >> 6, lane = tid & 63;
    const int lr = lane & 15, q = lane >> 4;
    // XCD-contiguous swizzle: XCD x gets row-tiles [x*64, x*64+64)
    const int tile = (blockIdx.x >> 3) + (blockIdx.x & 7) * 64;
    const int gm0  = tile << 5;             // 32 rows per block
    const int b    = gm0 >> 9;
    const int rh   = wave >> 1;             // row half (16 rows)
    const int chn  = wave & 1;              // col half (96 cols)

    const float* aP = ctx + (size_t)(gm0 + rh * 16 + lr) * H_ + q * 8;
    const unsigned short* bQ = Wt3 + (chn * 96 + lr) * 32 + q * 8;

    floatx4 acc[6];
#pragma unroll
    for (int t = 0; t < 6; t++) acc[t] = (floatx4){0.f, 0.f, 0.f, 0.f};

    // 8 batches of 4 k-iterations; all 32 loads of a batch issue before
    // any consume -> deep memory queue.
    for (int ob = 0; ob < 8; ++ob) {
        float4 a0[4], a1[4];
        short8 bb[4][6];
#pragma unroll
        for (int u = 0; u < 4; u++) {
            a0[u] = *(const float4*)(aP + u * 32);
            a1[u] = *(const float4*)(aP + u * 32 + 4);
#pragma unroll
            for (int t = 0; t < 6; t++)
                bb[u][t] = *(const short8*)(bQ + u * (NPAD * 32) + t * 512);
        }
        aP += 128;
        bQ += 4 * NPAD * 32;
#pragma unroll
        for (int u = 0; u < 4; u++) {
            short8 af;
            af[0] = (short)f2bf(a0[u].x); af[1] = (short)f2bf(a0[u].y);
            af[2] = (short)f2bf(a0[u].z); af[3] = (short)f2bf(a0[u].w);
            af[4] = (short)f2bf(a1[u].x); af[5] = (short)f2bf(a1[u].y);
            af[6] = (short)f2bf(a1[u].z); af[7] = (short)f2bf(a1[u].w);
#pragma unroll
            for (int t = 0; t < 6; t++)
                acc[t] = __builtin_amdgcn_mfma_f32_16x16x32_bf16(af, bb[u][t], acc[t], 0, 0, 0);
        }
    }

    // epilogue: logits -> BCE * mask -> per-wave reduce -> atomic
    float lsum = 0.0f;
#pragma unroll
    for (int t = 0; t < 6; t++) {
        const int col = chn * 96 + t * 16 + lr;
        if (col < NVALID) {
            const float rb = rowBias[b * NPAD + col];
#pragma unroll
            for (int i = 0; i < 4; i++) {
                const int row = gm0 + rh * 16 + q * 4 + i;
                const float l = acc[t][i] + rb;
                float tgt;
                if (col < 64)        tgt = oh[row * R_ + col];
                else if (col < 128)  tgt = ot[row * R_ + (col - 64)];
                else if (col == 128) tgt = ash[row];
                else                 tgt = ast[row];
                const float bce = fmaxf(l, 0.0f) - l * tgt
                                + log1pf(__expf(-fabsf(l)));
                lsum += bce * masks[row];
            }
        }
    }
#pragma unroll
    for (int o = 32; o > 0; o >>= 1) lsum += __shfl_down(lsum, o, 64);
    if (lane == 0) rbuf[wave] = lsum;

    // mask sum: wave 0 covers this block's 32 rows
    if (wave == 0) {
        float mv = (lane < 32) ? masks[gm0 + lane] : 0.0f;
#pragma unroll
        for (int o = 32; o > 0; o >>= 1) mv += __shfl_down(mv, o, 64);
        if (lane == 0) atomicAdd(&accum[1], mv);
    }

    __syncthreads();
    if (tid == 0) {
        atomicAdd(&accum[0], rbuf[0] + rbuf[1] + rbuf[2] + rbuf[3]);
        __threadfence();
        const int old = atomicAdd(ticket, 1);
        if (old == NBLK - 1) {
            const float s = atomicAdd(&accum[0], 0.0f);   // coherent read
            const float m = atomicAdd(&accum[1], 0.0f);
            out[0] = s / m;
        }
    }
}

extern "C" void kernel_launch(void* const* d_in, const int* in_sizes, int n_in,
                              void* d_out, int out_size, void* d_ws, size_t ws_size,
                              hipStream_t stream) {
    const float* ctx   = (const float*)d_in[0];
    const float* masks = (const float*)d_in[1];
    const float* ash   = (const float*)d_in[2];
    const float* ast   = (const float*)d_in[3];
    const float* sh    = (const float*)d_in[4];
    const float* st    = (const float*)d_in[5];
    const float* oh    = (const float*)d_in[6];
    const float* ot    = (const float*)d_in[7];
    const float* Ws_h  = (const float*)d_in[8];
    const float* bs_h  = (const float*)d_in[9];
    const float* Ws_t  = (const float*)d_in[10];
    const float* bs_t  = (const float*)d_in[11];
    const float* Wo_h  = (const float*)d_in[12];
    const float* bo_h  = (const float*)d_in[13];
    const float* Wo_t  = (const float*)d_in[14];
    const float* bo_t  = (const float*)d_in[15];
    float* out = (float*)d_out;

    char* ws = (char*)d_ws;
    float* accum   = (float*)(ws + 0);          // [0]=loss sum, [1]=mask sum
    int*   ticket  = (int*)(ws + 64);
    float* rowBias = (float*)(ws + 256);        // [32][192] fp32
    unsigned short* Wt3 = (unsigned short*)(ws + 256 + 32 * NPAD * 4); // [32][192][32] bf16

    prep_kernel<<<NPAD + B_, 256, 0, stream>>>(ctx, sh, st, Ws_h, Ws_t,
                                               Wo_h, Wo_t, bo_h, bo_t, bs_h, bs_t,
                                               Wt3, rowBias, accum, ticket);
    main_kernel<<<NBLK, 256, 0, stream>>>(ctx, Wt3, rowBias, masks,
                                          ash, ast, oh, ot, accum, ticket, out);
}